// Round 6
// baseline (9467.713 us; speedup 1.0000x reference)
//
#include <hip/hip_runtime.h>
#include <cstdint>
#include <cstddef>

// LSTM: IC=HC=512, L=2, T=512, BS=64.  out = [T,64,512] fp32, hs/cs = [2,64,512] fp32.
// R7: XCD-local recurrence exchange, HANG-PROOF edition of R6.
//   4 domains = {layer} x {batch half}: 32 WGs each, expected co-located one-per-XCD
//   via blockIdx%8 residues 0..3 (residues 4..7 exit).  Fast path: h + flags through
//   the shared per-XCD L2 (inline-asm sc0).  EVERY fast-path spin is BOUNDED; on
//   timeout the WG permanently falls back to the R5-proven MALL/canary path
//   (producers always dual-store: sc0 ring + agent-atomic mirror).  Placement is
//   verified via HW_REG_XCC_ID (bounded).  No counted-vmcnt tricks: only vmcnt(0)
//   + sched_barrier after asm groups; layer1's h0(t) prefetch overlap uses
//   compiler-tracked agent atomics (compiler inserts correct waits).

#define T_STEPS 512
#define WROW 1032                    // Wl row stride (bf16): 1024 + 8 pad
#define CAN64 0x7FC07FC07FC07FC0ULL
#define POLL_BOUND 4096
#define PLC_BOUND  (1 << 20)

typedef float f32x4 __attribute__((ext_vector_type(4)));
typedef short s16x8 __attribute__((ext_vector_type(8)));
typedef unsigned int u32x4 __attribute__((ext_vector_type(4)));

__device__ __forceinline__ unsigned short f2bf(float f) {
    unsigned int u = __builtin_bit_cast(unsigned int, f);
    u += 0x7FFFu + ((u >> 16) & 1u);          // round-to-nearest-even
    return (unsigned short)(u >> 16);
}
__device__ __forceinline__ float sig_(float x)  { return 1.0f / (1.0f + __expf(-x)); }
__device__ __forceinline__ float tanh_(float x) { return 1.0f - 2.0f / (__expf(2.0f * x) + 1.0f); }

// ---- PROVEN (R5) agent-scope primitives: MALL-coherent, compiler-tracked ----
__device__ __forceinline__ unsigned long long ld8(const unsigned short* p) {
    return __hip_atomic_load((unsigned long long*)p, __ATOMIC_RELAXED, __HIP_MEMORY_SCOPE_AGENT);
}
__device__ __forceinline__ void stc(unsigned short* p, s16x8 v) {
    ulonglong2 u = __builtin_bit_cast(ulonglong2, v);
    __hip_atomic_store((unsigned long long*)p,     u.x, __ATOMIC_RELAXED, __HIP_MEMORY_SCOPE_AGENT);
    __hip_atomic_store((unsigned long long*)p + 1, u.y, __ATOMIC_RELAXED, __HIP_MEMORY_SCOPE_AGENT);
}

// ---- fast-path (XCD L2) asm primitives ----------------------------------
__device__ __forceinline__ void ld16_sc0(s16x8* d_, const unsigned short* p) {
    asm volatile("global_load_dwordx4 %0, %1, off sc0" : "=v"(*d_) : "v"(p));
}
__device__ __forceinline__ void st16_sc0(unsigned short* p, s16x8 v) {
    asm volatile("global_store_dwordx4 %0, %1, off sc0" :: "v"(p), "v"(v) : "memory");
}
#define VMCNT0() do { asm volatile("s_waitcnt vmcnt(0)" ::: "memory"); \
                      __builtin_amdgcn_sched_barrier(0); } while (0)

// ---- prep kernels -------------------------------------------------------

__global__ void k_conv_bf16(const float* __restrict__ src, unsigned short* __restrict__ dst) {
    int i = (blockIdx.x * 256 + threadIdx.x) * 8;
    float4 a = *(const float4*)(src + i);
    float4 b = *(const float4*)(src + i + 4);
    s16x8 o;
    o[0]=(short)f2bf(a.x); o[1]=(short)f2bf(a.y); o[2]=(short)f2bf(a.z); o[3]=(short)f2bf(a.w);
    o[4]=(short)f2bf(b.x); o[5]=(short)f2bf(b.y); o[6]=(short)f2bf(b.z); o[7]=(short)f2bf(b.w);
    *(s16x8*)(dst + i) = o;
}

__global__ void k_transpose_w(const float* __restrict__ W0, const float* __restrict__ W1,
                              unsigned short* __restrict__ WT0, unsigned short* __restrict__ WT1) {
    __shared__ unsigned short tile[32][33];
    const float* W = blockIdx.z ? W1 : W0;
    unsigned short* WT = blockIdx.z ? WT1 : WT0;
    int n0 = blockIdx.x * 32, k0 = blockIdx.y * 32;
    int tx = threadIdx.x, ty = threadIdx.y;       // (32,8)
    #pragma unroll
    for (int i = 0; i < 4; i++)
        tile[ty + i*8][tx] = f2bf(W[(size_t)(k0 + ty + i*8) * 2048 + n0 + tx]);
    __syncthreads();
    #pragma unroll
    for (int i = 0; i < 4; i++)
        WT[(size_t)(n0 + ty + i*8) * 1024 + k0 + tx] = tile[tx][ty + i*8];
}

__global__ void k_fill_canary(unsigned long long* __restrict__ dst) {
    size_t i = ((size_t)blockIdx.x * 256 + threadIdx.x) * 2;
    dst[i] = CAN64; dst[i + 1] = CAN64;
}

// initial h into ring slot 3 of each domain: tile layout [jb 64][bl 32][8]
__global__ void k_hinit2(const float* __restrict__ h0, unsigned short* __restrict__ ring) {
    int idx = blockIdx.x * 256 + threadIdx.x;     // 65536
    int d = idx >> 14;
    int r = idx & 16383;
    int jb = r >> 8;
    int e = r & 7;
    ring[(size_t)(d * 4 + 3) * 16384 + r] = f2bf(h0[(d >> 1) * 512 + jb * 8 + e]);
}

// ---- fused persistent recurrence kernel ---------------------------------
__global__ __launch_bounds__(256, 1) void k_lstm_fused7(
    const unsigned short* __restrict__ xb,
    const unsigned short* __restrict__ WT0, const unsigned short* __restrict__ WT1,
    const float* __restrict__ b0, const float* __restrict__ b1,
    const float* __restrict__ c0,
    unsigned short* __restrict__ h0m, unsigned short* __restrict__ h1m,
    unsigned short* __restrict__ ring, unsigned int* __restrict__ flags,
    unsigned int* __restrict__ plc,
    float* __restrict__ out, float* __restrict__ hs, float* __restrict__ cs)
{
    __shared__ unsigned short Wl[64][WROW];      // 132,096 B
    __shared__ unsigned short hst[32][16];       //   1,024 B

    const int d = (int)(blockIdx.x & 7);
    if (d >= 4) return;                          // residues 4..7: exit, free the CU
    const int wid = (int)(blockIdx.x >> 3);      // 0..31 within domain
    const int tid = (int)threadIdx.x;
    const int layer = d >> 1;
    const int bt    = d & 1;
    const int j0    = wid * 16;

    {   // stage weights: 64 rows (gate*16 + jl) x 1024 K
        const unsigned short* WT = layer ? WT1 : WT0;
        #pragma unroll
        for (int it = 0; it < 32; it++) {
            int idx = it * 256 + tid;            // 0..8191
            int row = idx >> 7;                  // 0..63
            int ch  = idx & 127;                 // 0..127
            int gate = row >> 4, jl = row & 15;
            *(s16x8*)(&Wl[row][ch * 8]) =
                *(const s16x8*)(WT + (size_t)(gate * 512 + j0 + jl) * 1024 + ch * 8);
        }
    }
    __syncthreads();

    const int lane = tid & 63;
    const int wv   = tid >> 6;
    const int mh   = wv >> 1;                    // batch-16 half
    const int jo   = wv & 1;                     // j-octet
    const int q    = lane >> 4;
    const int cc   = lane & 15;
    const int jj   = j0 + jo * 8 + (cc & 7);
    const int w0row = ((cc < 8) ? 0 : 16) + jo * 8 + (cc & 7);   // [f|i]
    const int w1row = w0row + 32;                                // [o|g]

    const float* bias = layer ? b1 : b0;
    const float bt0 = (cc < 8) ? bias[jj] : bias[512 + jj];
    const float bt1 = (cc < 8) ? bias[1024 + jj] : bias[1536 + jj];
    float cst[4];
    { float ci = c0[layer * 512 + jj]; cst[0]=cst[1]=cst[2]=cst[3]=ci; }

    unsigned int* myf = flags + (size_t)(d * 32 + wid) * 4 + wv;
    unsigned short* hmL = layer ? h1m : h0m;     // this layer's MALL mirror
    unsigned short* ringd = ring + (size_t)d * 4 * 16384;

    // ---- placement verification (bounded; never assume WG->XCD mapping) ----
    unsigned myxcd;
    asm volatile("s_getreg_b32 %0, hwreg(HW_REG_XCC_ID)" : "=s"(myxcd));
    if (tid == 0)
        __hip_atomic_store(plc + d * 32 + wid, myxcd + 1u,
                           __ATOMIC_RELAXED, __HIP_MEMORY_SCOPE_AGENT);
    bool fastok;
    {
        unsigned pv = 1u;
        int spins = 0; bool got = true;
        while (true) {
            if (lane < 32)
                pv = __hip_atomic_load(plc + d * 32 + lane, __ATOMIC_RELAXED, __HIP_MEMORY_SCOPE_AGENT);
            if (__ballot(pv == 0u) == 0ull) break;
            if (++spins > PLC_BOUND) { got = false; break; }
            __builtin_amdgcn_s_sleep(8);
        }
        fastok = got && (__ballot(lane < 32 && pv != myxcd + 1u) == 0ull);
    }

    for (int t = 0; t < T_STEPS; t++) {
        f32x4 a0  = {bt0, bt0, bt0, bt0};
        f32x4 a1  = {bt1, bt1, bt1, bt1};
        f32x4 a0b = {0.f, 0.f, 0.f, 0.f};
        f32x4 a1b = {0.f, 0.f, 0.f, 0.f};
        s16x8 afr[16];   // recurrent-half fragments h_own(t-1)
        s16x8 axh[16];   // first-half fragments (l0: x(t); l1: h0(t))
        const size_t frch[1] = {0};  (void)frch;

        // ================= acquire own-layer h(t-1) =================
        if (t == 0) {
            const unsigned short* rp = ringd + (size_t)3 * 16384;
            #pragma unroll
            for (int kk = 0; kk < 16; kk++) {
                const unsigned short* p = rp + ((size_t)(kk * 4 + q) * 32 + mh * 16 + cc) * 8;
                unsigned long long lo = ld8(p), hi = ld8(p + 4);
                ulonglong2 u; u.x = lo; u.y = hi;
                afr[kk] = __builtin_bit_cast(s16x8, u);
            }
        } else {
            bool have = false;
            if (fastok) {
                // bounded flag poll: all 32 WGs of this domain completed step t-1
                const unsigned int* fp = flags + (size_t)(d * 32 + (lane & 31)) * 4;
                int spins = 0; bool okp = true;
                while (true) {
                    u32x4 fv;
                    asm volatile("global_load_dwordx4 %0, %1, off sc0" : "=v"(fv) : "v"(fp));
                    asm volatile("s_waitcnt vmcnt(0)" ::: "memory");
                    __builtin_amdgcn_sched_barrier(0);
                    unsigned m0 = fv[0] < fv[1] ? fv[0] : fv[1];
                    unsigned m1 = fv[2] < fv[3] ? fv[2] : fv[3];
                    unsigned m  = m0 < m1 ? m0 : m1;
                    if (__ballot(m < (unsigned)t) == 0ull) break;
                    if (++spins > POLL_BOUND) { okp = false; break; }
                    __builtin_amdgcn_s_sleep(1);
                }
                if (okp) {
                    const unsigned short* rp = ringd + (size_t)((t + 3) & 3) * 16384;
                    #pragma unroll
                    for (int kk = 0; kk < 16; kk++)
                        ld16_sc0(&afr[kk], rp + ((size_t)(kk * 4 + q) * 32 + mh * 16 + cc) * 8);
                    VMCNT0();
                    have = true;
                } else {
                    fastok = false;   // permanent demotion; no hang possible
                }
            }
            if (!have) {
                // R5-PROVEN canary sweep of the MALL mirror (unbounded but proven-live)
                const unsigned short* hb = hmL + ((size_t)(t - 1) * 2 + bt) * 16384;
                bool ok = true;
                #pragma unroll
                for (int kk = 0; kk < 16; kk++) {
                    const unsigned short* p = hb + ((size_t)(kk * 4 + q) * 32 + mh * 16 + cc) * 8;
                    unsigned long long lo = ld8(p), hi = ld8(p + 4);
                    ok = ok & (lo != CAN64) & (hi != CAN64);
                    ulonglong2 u; u.x = lo; u.y = hi;
                    afr[kk] = __builtin_bit_cast(s16x8, u);
                }
                while (!ok) {
                    __builtin_amdgcn_s_sleep(1);
                    ok = true;
                    #pragma unroll
                    for (int kk = 0; kk < 16; kk++) {
                        const unsigned short* p = hb + ((size_t)(kk * 4 + q) * 32 + mh * 16 + cc) * 8;
                        unsigned long long lo = ld8(p), hi = ld8(p + 4);
                        ok = ok & (lo != CAN64) & (hi != CAN64);
                        ulonglong2 u; u.x = lo; u.y = hi;
                        afr[kk] = __builtin_bit_cast(s16x8, u);
                    }
                }
            }
        }

        if (layer == 0) {
            // x fragments: pure input, cached path (bf16, pre-converted)
            const unsigned short* xp = xb + (size_t)(t * 64 + bt * 32 + mh * 16 + cc) * 512 + q * 8;
            #pragma unroll
            for (int kk = 0; kk < 16; kk++)
                axh[kk] = *(const s16x8*)(xp + kk * 32);
        } else {
            // h0(t) sweep via PROVEN agent atomics; compiler schedules/waits correctly,
            // overlapping these loads with the h-half MFMAs below.
            const unsigned short* hp = h0m + ((size_t)t * 2 + bt) * 16384;
            bool ok0 = true;
            #pragma unroll
            for (int kk = 0; kk < 16; kk++) {
                const unsigned short* p = hp + ((size_t)(kk * 4 + q) * 32 + mh * 16 + cc) * 8;
                unsigned long long lo = ld8(p), hi = ld8(p + 4);
                ok0 = ok0 & (lo != CAN64) & (hi != CAN64);
                ulonglong2 u; u.x = lo; u.y = hi;
                axh[kk] = __builtin_bit_cast(s16x8, u);
            }
            // h-half (own recurrent) MFMAs first: K 512..1023 with afr
            #pragma unroll
            for (int kk = 0; kk < 16; kk += 2) {
                s16x8 w00 = *(const s16x8*)(&Wl[w0row][512 + kk * 32 + q * 8]);
                s16x8 w10 = *(const s16x8*)(&Wl[w1row][512 + kk * 32 + q * 8]);
                a0  = __builtin_amdgcn_mfma_f32_16x16x32_bf16(afr[kk], w00, a0, 0, 0, 0);
                a1  = __builtin_amdgcn_mfma_f32_16x16x32_bf16(afr[kk], w10, a1, 0, 0, 0);
                s16x8 w01 = *(const s16x8*)(&Wl[w0row][512 + (kk + 1) * 32 + q * 8]);
                s16x8 w11 = *(const s16x8*)(&Wl[w1row][512 + (kk + 1) * 32 + q * 8]);
                a0b = __builtin_amdgcn_mfma_f32_16x16x32_bf16(afr[kk + 1], w01, a0b, 0, 0, 0);
                a1b = __builtin_amdgcn_mfma_f32_16x16x32_bf16(afr[kk + 1], w11, a1b, 0, 0, 0);
            }
            // retry h0(t) until fresh (R5-proven liveness)
            while (!ok0) {
                __builtin_amdgcn_s_sleep(1);
                ok0 = true;
                #pragma unroll
                for (int kk = 0; kk < 16; kk++) {
                    const unsigned short* p = hp + ((size_t)(kk * 4 + q) * 32 + mh * 16 + cc) * 8;
                    unsigned long long lo = ld8(p), hi = ld8(p + 4);
                    ok0 = ok0 & (lo != CAN64) & (hi != CAN64);
                    ulonglong2 u; u.x = lo; u.y = hi;
                    axh[kk] = __builtin_bit_cast(s16x8, u);
                }
            }
        }

        // first-half MFMAs: K 0..511 with axh (l0: x(t); l1: h0(t))
        #pragma unroll
        for (int kk = 0; kk < 16; kk += 2) {
            s16x8 w00 = *(const s16x8*)(&Wl[w0row][kk * 32 + q * 8]);
            s16x8 w10 = *(const s16x8*)(&Wl[w1row][kk * 32 + q * 8]);
            a0  = __builtin_amdgcn_mfma_f32_16x16x32_bf16(axh[kk], w00, a0, 0, 0, 0);
            a1  = __builtin_amdgcn_mfma_f32_16x16x32_bf16(axh[kk], w10, a1, 0, 0, 0);
            s16x8 w01 = *(const s16x8*)(&Wl[w0row][(kk + 1) * 32 + q * 8]);
            s16x8 w11 = *(const s16x8*)(&Wl[w1row][(kk + 1) * 32 + q * 8]);
            a0b = __builtin_amdgcn_mfma_f32_16x16x32_bf16(axh[kk + 1], w01, a0b, 0, 0, 0);
            a1b = __builtin_amdgcn_mfma_f32_16x16x32_bf16(axh[kk + 1], w11, a1b, 0, 0, 0);
        }
        if (layer == 0) {
            // h-half MFMAs for layer0: K 512..1023 with afr
            #pragma unroll
            for (int kk = 0; kk < 16; kk += 2) {
                s16x8 w00 = *(const s16x8*)(&Wl[w0row][512 + kk * 32 + q * 8]);
                s16x8 w10 = *(const s16x8*)(&Wl[w1row][512 + kk * 32 + q * 8]);
                a0  = __builtin_amdgcn_mfma_f32_16x16x32_bf16(afr[kk], w00, a0, 0, 0, 0);
                a1  = __builtin_amdgcn_mfma_f32_16x16x32_bf16(afr[kk], w10, a1, 0, 0, 0);
                s16x8 w01 = *(const s16x8*)(&Wl[w0row][512 + (kk + 1) * 32 + q * 8]);
                s16x8 w11 = *(const s16x8*)(&Wl[w1row][512 + (kk + 1) * 32 + q * 8]);
                a0b = __builtin_amdgcn_mfma_f32_16x16x32_bf16(afr[kk + 1], w01, a0b, 0, 0, 0);
                a1b = __builtin_amdgcn_mfma_f32_16x16x32_bf16(afr[kk + 1], w11, a1b, 0, 0, 0);
            }
        }

        // ---- activation (R1 math) ----
        a0 = a0 + a0b;
        a1 = a1 + a1b;
        float hvr[4], cnr[4];
        #pragma unroll
        for (int r = 0; r < 4; r++) {
            float z0 = a0[r], z1 = a1[r];
            float p0 = __shfl_xor(z0, 8, 64);
            float p1 = __shfl_xor(z1, 8, 64);
            float zf = (cc < 8) ? z0 : p0;
            float zi = (cc < 8) ? p0 : z0;
            float zo = (cc < 8) ? z1 : p1;
            float zg = (cc < 8) ? p1 : z1;
            float fg = sig_(zf + 1.0f);            // FORGET_BIAS
            float ig = sig_(zi);
            float og = sig_(zo);
            float gg = tanh_(zg);
            float cn = cst[r] * fg + gg * ig;
            cst[r] = cn;
            float hv = og * tanh_(cn);
            hvr[r] = hv; cnr[r] = cn;
            if (cc < 8) hst[mh * 16 + q * 4 + r][jo * 8 + cc] = f2bf(hv);
        }

        // ---- dual flush: sc0 ring (L2 fast) + PROVEN agent-atomic mirror ----
        if (lane < 16) {
            s16x8 hv16 = *(const s16x8*)(&hst[mh * 16 + lane][jo * 8]);
            size_t ch = (size_t)((wid * 2 + jo) * 32 + mh * 16 + lane) * 8;
            st16_sc0(ringd + (size_t)(t & 3) * 16384 + ch, hv16);
            stc(hmL + ((size_t)t * 2 + bt) * 16384 + ch, hv16);
        }
        VMCNT0();                                 // all h stores ack'd
        if (lane == 0) {
            unsigned fvv = (unsigned)(t + 1);
            asm volatile("global_store_dword %0, %1, off sc0" :: "v"(myf), "v"(fvv) : "memory");
        }

        // ---- non-critical stores after the flag ----
        if (layer == 1 && cc >= 8) {
            #pragma unroll
            for (int r = 0; r < 4; r++) {
                int bg = bt * 32 + mh * 16 + q * 4 + r;
                out[((size_t)t * 64 + bg) * 512 + jj] = hvr[r];
            }
        }
        if (t == T_STEPS - 1) {
            #pragma unroll
            for (int r = 0; r < 4; r++) {
                int bg = bt * 32 + mh * 16 + q * 4 + r;
                if (cc < 8) hs[((size_t)layer * 64 + bg) * 512 + jj] = hvr[r];
                else        cs[((size_t)layer * 64 + bg) * 512 + jj] = cnr[r];
            }
        }
    }
}

// ---- launch -------------------------------------------------------------

extern "C" void kernel_launch(void* const* d_in, const int* in_sizes, int n_in,
                              void* d_out, int out_size, void* d_ws, size_t ws_size,
                              hipStream_t stream) {
    const float* x  = (const float*)d_in[0];
    const float* W0 = (const float*)d_in[1];
    const float* b0 = (const float*)d_in[2];
    const float* W1 = (const float*)d_in[3];
    const float* b1 = (const float*)d_in[4];
    const float* h0 = (const float*)d_in[5];
    const float* c0 = (const float*)d_in[6];
    float* out = (float*)d_out;

    char* ws = (char*)d_ws;
    unsigned short* xb   = (unsigned short*)(ws);                    // 33,554,432 B
    unsigned short* WT0  = (unsigned short*)(ws + 33554432);         //  4,194,304 B
    unsigned short* WT1  = (unsigned short*)(ws + 37748736);         //  4,194,304 B
    unsigned short* h0m  = (unsigned short*)(ws + 41943040);         // 33,554,432 B (canary mirror)
    unsigned short* h1m  = (unsigned short*)(ws + 75497472);         // 33,554,432 B (canary mirror)
    unsigned short* ring = (unsigned short*)(ws + 109051904);        //    524,288 B (L2 ring)
    unsigned int*   flags = (unsigned int*)(ws + 109576192);         //      2,048 B
    unsigned int*   plc   = (unsigned int*)(ws + 109578240);         //        512 B

    hipMemsetAsync(flags, 0, 4096, stream);                          // flags + plc
    k_fill_canary<<<16384, 256, 0, stream>>>((unsigned long long*)h0m);  // h0m+h1m (64 MB)
    k_conv_bf16<<<8192, 256, 0, stream>>>(x, xb);
    k_transpose_w<<<dim3(64, 32, 2), dim3(32, 8), 0, stream>>>(W0, W1, WT0, WT1);
    k_hinit2<<<256, 256, 0, stream>>>(h0, ring);

    float* hs = out + 16777216;            // [2][64][512]
    float* cs = hs + 65536;                // [2][64][512]
    k_lstm_fused7<<<256, 256, 0, stream>>>(xb, WT0, WT1, b0, b1, c0,
                                           h0m, h1m, ring, flags, plc, out, hs, cs);
}

// Round 7
// 4452.174 us; speedup vs baseline: 2.1265x; 2.1265x over previous
//
#include <hip/hip_runtime.h>
#include <cstdint>
#include <cstddef>

// LSTM: IC=HC=512, L=2, T=512, BS=64.  out = [T,64,512] fp32, hs/cs = [2,64,512] fp32.
// R8: R5 skeleton (flag-free "data is the flag" canary protocol, fire-and-forget
//     agent-scope h stores, 128 WGs: blocks 0..63 layer0 / 64..127 layer1) plus:
//     (a) PER-CHUNK pipelined h consumption: issue all 32 8B-atomic loads, then
//         per 16B chunk {progressive wait, spin-if-canary, 2 MFMAs}.  K-accum is
//         commutative, so producer skew only delays that chunk's MFMA and the
//         retry load storm shrinks to the actually-late chunks.
//     (b) x(t+1) prefetched into registers during step t (removes serial HBM
//         x-load latency from the recurrence path).

#define T_STEPS 512
#define WROW 1032   // LDS row stride (bf16 elems): 1024 + 8 pad
#define CAN64 0x7FC07FC07FC07FC0ULL

typedef float f32x4 __attribute__((ext_vector_type(4)));
typedef short s16x8 __attribute__((ext_vector_type(8)));

__device__ __forceinline__ unsigned short f2bf(float f) {
    unsigned int u = __builtin_bit_cast(unsigned int, f);
    u += 0x7FFFu + ((u >> 16) & 1u);          // round-to-nearest-even
    return (unsigned short)(u >> 16);
}
__device__ __forceinline__ float sig_(float x)  { return 1.0f / (1.0f + __expf(-x)); }
__device__ __forceinline__ float tanh_(float x) { return 1.0f - 2.0f / (__expf(2.0f * x) + 1.0f); }

// Coherent (agent-scope, MALL) 8B atomic load/store primitives (R5-proven).
__device__ __forceinline__ unsigned long long ld8(const unsigned short* p) {
    return __hip_atomic_load((unsigned long long*)p, __ATOMIC_RELAXED, __HIP_MEMORY_SCOPE_AGENT);
}
__device__ __forceinline__ void stc(unsigned short* p, s16x8 v) {
    ulonglong2 u = __builtin_bit_cast(ulonglong2, v);
    __hip_atomic_store((unsigned long long*)p,     u.x, __ATOMIC_RELAXED, __HIP_MEMORY_SCOPE_AGENT);
    __hip_atomic_store((unsigned long long*)p + 1, u.y, __ATOMIC_RELAXED, __HIP_MEMORY_SCOPE_AGENT);
}

// ---- prep kernels -------------------------------------------------------

__global__ void k_conv_bf16(const float* __restrict__ src, unsigned short* __restrict__ dst) {
    int i = (blockIdx.x * 256 + threadIdx.x) * 8;
    float4 a = *(const float4*)(src + i);
    float4 b = *(const float4*)(src + i + 4);
    s16x8 o;
    o[0]=(short)f2bf(a.x); o[1]=(short)f2bf(a.y); o[2]=(short)f2bf(a.z); o[3]=(short)f2bf(a.w);
    o[4]=(short)f2bf(b.x); o[5]=(short)f2bf(b.y); o[6]=(short)f2bf(b.z); o[7]=(short)f2bf(b.w);
    *(s16x8*)(dst + i) = o;
}

__global__ void k_transpose_w(const float* __restrict__ W0, const float* __restrict__ W1,
                              unsigned short* __restrict__ WT0, unsigned short* __restrict__ WT1) {
    __shared__ unsigned short tile[32][33];
    const float* W = blockIdx.z ? W1 : W0;
    unsigned short* WT = blockIdx.z ? WT1 : WT0;
    int n0 = blockIdx.x * 32, k0 = blockIdx.y * 32;
    int tx = threadIdx.x, ty = threadIdx.y;       // (32,8)
    #pragma unroll
    for (int i = 0; i < 4; i++)
        tile[ty + i*8][tx] = f2bf(W[(size_t)(k0 + ty + i*8) * 2048 + n0 + tx]);
    __syncthreads();
    #pragma unroll
    for (int i = 0; i < 4; i++)
        WT[(size_t)(n0 + ty + i*8) * 1024 + k0 + tx] = tile[tx][ty + i*8];
}

__global__ void k_hinit(const float* __restrict__ h0, unsigned short* __restrict__ hi0,
                        unsigned short* __restrict__ hi1) {
    int idx = blockIdx.x * 256 + threadIdx.x;   // 65536 total
    int layer = idx >> 15;
    int r = idx & 32767;
    int b = r >> 9;
    int j = r & 511;
    unsigned short v = f2bf(h0[layer * 512 + j]);
    unsigned short* d = layer ? hi1 : hi0;
    d[(size_t)((j >> 3) * 64 + b) * 8 + (j & 7)] = v;
}

// canary-fill h0s+h1s (64 MB contiguous): 16B per thread
__global__ void k_fill_canary(unsigned long long* __restrict__ dst) {
    size_t i = ((size_t)blockIdx.x * 256 + threadIdx.x) * 2;
    dst[i]     = CAN64;
    dst[i + 1] = CAN64;
}

// ---- fused persistent recurrence kernel ---------------------------------
// blockIdx 0..63 = layer 0, 64..127 = layer 1; wg = blockIdx&63 owns hidden cols 8wg..+7.
__global__ __launch_bounds__(256, 1) void k_lstm_fused8(
    const unsigned short* __restrict__ xb,
    const unsigned short* __restrict__ hi0, const unsigned short* __restrict__ hi1,
    const unsigned short* __restrict__ WT0, const unsigned short* __restrict__ WT1,
    const float* __restrict__ b0, const float* __restrict__ b1,
    const float* __restrict__ c0,
    unsigned short* __restrict__ h0s, unsigned short* __restrict__ h1s,
    float* __restrict__ out, float* __restrict__ hs, float* __restrict__ cs)
{
    __shared__ unsigned short Wl[32][WROW];
    __shared__ unsigned short hst[64][8];

    const int isl1 = (int)(blockIdx.x >> 6);
    const int wg   = (int)(blockIdx.x & 63);
    const int tid  = (int)threadIdx.x;
    const int j0   = wg * 8;

    {   // stage this layer's full W (K=1024): 32 rows x 1024 bf16
        const unsigned short* WT = isl1 ? WT1 : WT0;
        #pragma unroll
        for (int it = 0; it < 16; it++) {
            int idx = it * 256 + tid;
            int row = idx >> 7;
            int ch  = idx & 127;
            int gate = (row >> 4) * 2 + ((row & 15) >> 3);   // 0:f 1:i 2:o 3:g
            int gr = gate * 512 + j0 + (row & 7);
            *(s16x8*)(&Wl[row][ch * 8]) = *(const s16x8*)(WT + (size_t)gr * 1024 + ch * 8);
        }
    }
    __syncthreads();

    const int lane = tid & 63;
    const int wv   = tid >> 6;
    const int q    = lane >> 4;
    const int cc   = lane & 15;
    const int arow = wv * 16 + cc;
    const int jj   = j0 + (cc & 7);
    const int bb   = wv * 16 + q * 4;

    const float* bias = isl1 ? b1 : b0;
    const float bt0 = (cc < 8) ? bias[jj] : bias[512 + jj];          // [f|i]
    const float bt1 = (cc < 8) ? bias[1024 + jj] : bias[1536 + jj];  // [o|g]
    float cst[4];
    { float ci = c0[isl1 * 512 + jj]; cst[0]=cst[1]=cst[2]=cst[3]=ci; }

    if (!isl1) {
        // ================= layer 0 =================
        // preload x(0) into registers
        s16x8 ax[16];
        {
            const unsigned short* xp = xb + (size_t)(0 * 64 + arow) * 512 + q * 8;
            #pragma unroll
            for (int kk = 0; kk < 16; kk++)
                ax[kk] = *(const s16x8*)(xp + kk * 32);
        }

        for (int t = 0; t < T_STEPS; t++) {
            // 1. issue h0(t-1) sweep loads (no checks yet -> loads pipeline)
            s16x8 ah[16];
            const unsigned short* hb = t ? (h0s + (size_t)(t - 1) * 32768) : hi0;
            #pragma unroll
            for (int kk = 0; kk < 16; kk++) {
                const unsigned short* p = hb + ((size_t)(kk * 4 + q) * 64 + arow) * 8;
                ulonglong2 u; u.x = ld8(p); u.y = ld8(p + 4);
                ah[kk] = __builtin_bit_cast(s16x8, u);
            }

            // 2. x-half MFMAs (ax already in registers -> no memory wait)
            f32x4 a0  = {bt0, bt0, bt0, bt0};
            f32x4 a1  = {bt1, bt1, bt1, bt1};
            f32x4 a0b = {0.f, 0.f, 0.f, 0.f};
            f32x4 a1b = {0.f, 0.f, 0.f, 0.f};
            #pragma unroll
            for (int kk = 0; kk < 16; kk += 2) {       // K 0..511 : x(t)
                s16x8 w00 = *(const s16x8*)(&Wl[cc][kk * 32 + q * 8]);
                s16x8 w10 = *(const s16x8*)(&Wl[16 + cc][kk * 32 + q * 8]);
                a0  = __builtin_amdgcn_mfma_f32_16x16x32_bf16(ax[kk], w00, a0, 0, 0, 0);
                a1  = __builtin_amdgcn_mfma_f32_16x16x32_bf16(ax[kk], w10, a1, 0, 0, 0);
                s16x8 w01 = *(const s16x8*)(&Wl[cc][(kk + 1) * 32 + q * 8]);
                s16x8 w11 = *(const s16x8*)(&Wl[16 + cc][(kk + 1) * 32 + q * 8]);
                a0b = __builtin_amdgcn_mfma_f32_16x16x32_bf16(ax[kk + 1], w01, a0b, 0, 0, 0);
                a1b = __builtin_amdgcn_mfma_f32_16x16x32_bf16(ax[kk + 1], w11, a1b, 0, 0, 0);
            }

            // 3. issue x(t+1) prefetch (completes during h wait / activation)
            {
                int tn = (t + 1 < T_STEPS) ? (t + 1) : t;
                const unsigned short* xp = xb + (size_t)(tn * 64 + arow) * 512 + q * 8;
                #pragma unroll
                for (int kk = 0; kk < 16; kk++)
                    ax[kk] = *(const s16x8*)(xp + kk * 32);
            }

            // 4. per-chunk: progressive wait + spin-if-canary + 2 MFMAs (K 512..1023)
            #pragma unroll
            for (int kk = 0; kk < 16; kk++) {
                const unsigned short* p = hb + ((size_t)(kk * 4 + q) * 64 + arow) * 8;
                ulonglong2 u = __builtin_bit_cast(ulonglong2, ah[kk]);
                while ((u.x == CAN64) | (u.y == CAN64)) {
                    __builtin_amdgcn_s_sleep(1);
                    u.x = ld8(p); u.y = ld8(p + 4);
                }
                s16x8 hf = __builtin_bit_cast(s16x8, u);
                s16x8 w00 = *(const s16x8*)(&Wl[cc][(16 + kk) * 32 + q * 8]);
                s16x8 w10 = *(const s16x8*)(&Wl[16 + cc][(16 + kk) * 32 + q * 8]);
                if (kk & 1) {
                    a0b = __builtin_amdgcn_mfma_f32_16x16x32_bf16(hf, w00, a0b, 0, 0, 0);
                    a1b = __builtin_amdgcn_mfma_f32_16x16x32_bf16(hf, w10, a1b, 0, 0, 0);
                } else {
                    a0  = __builtin_amdgcn_mfma_f32_16x16x32_bf16(hf, w00, a0, 0, 0, 0);
                    a1  = __builtin_amdgcn_mfma_f32_16x16x32_bf16(hf, w10, a1, 0, 0, 0);
                }
            }
            a0 = a0 + a0b;
            a1 = a1 + a1b;

            // 5. activation + staging + fire-and-forget flush
            #pragma unroll
            for (int r = 0; r < 4; r++) {
                float z0 = a0[r], z1 = a1[r];
                float p0 = __shfl_xor(z0, 8, 64);
                float p1 = __shfl_xor(z1, 8, 64);
                float zf = (cc < 8) ? z0 : p0;
                float zi = (cc < 8) ? p0 : z0;
                float zo = (cc < 8) ? z1 : p1;
                float zg = (cc < 8) ? p1 : z1;
                float fg = sig_(zf + 1.0f);            // FORGET_BIAS
                float ig = sig_(zi);
                float og = sig_(zo);
                float gg = tanh_(zg);
                float cn = cst[r] * fg + gg * ig;
                cst[r] = cn;
                float hv = og * tanh_(cn);
                int b = bb + r;
                if (cc < 8) hst[b][cc] = f2bf(hv);     // wave-local rows
                if (t == T_STEPS - 1) {
                    if (cc < 8) hs[(size_t)b * 512 + jj] = hv;
                    else        cs[(size_t)b * 512 + jj] = cn;
                }
            }
            if (lane < 16) {
                int row = wv * 16 + lane;
                stc(h0s + (size_t)t * 32768 + (size_t)wg * 512 + (size_t)row * 8,
                    *(const s16x8*)(&hst[row][0]));
            }
        }
    } else {
        // ================= layer 1 =================
        for (int t = 0; t < T_STEPS; t++) {
            // 1. issue h1(t-1) sweep loads
            s16x8 ah1[16];
            const unsigned short* hb1 = t ? (h1s + (size_t)(t - 1) * 32768) : hi1;
            #pragma unroll
            for (int kk = 0; kk < 16; kk++) {
                const unsigned short* p = hb1 + ((size_t)(kk * 4 + q) * 64 + arow) * 8;
                ulonglong2 u; u.x = ld8(p); u.y = ld8(p + 4);
                ah1[kk] = __builtin_bit_cast(s16x8, u);
            }
            // 2. issue h0(t) sweep loads (in flight during h1 processing)
            s16x8 ah0[16];
            const unsigned short* hb0 = h0s + (size_t)t * 32768;
            #pragma unroll
            for (int kk = 0; kk < 16; kk++) {
                const unsigned short* p = hb0 + ((size_t)(kk * 4 + q) * 64 + arow) * 8;
                ulonglong2 u; u.x = ld8(p); u.y = ld8(p + 4);
                ah0[kk] = __builtin_bit_cast(s16x8, u);
            }

            f32x4 a0  = {bt0, bt0, bt0, bt0};
            f32x4 a1  = {bt1, bt1, bt1, bt1};
            f32x4 a0b = {0.f, 0.f, 0.f, 0.f};
            f32x4 a1b = {0.f, 0.f, 0.f, 0.f};

            // 3. per-chunk h1(t-1): K 512..1023
            #pragma unroll
            for (int kk = 0; kk < 16; kk++) {
                const unsigned short* p = hb1 + ((size_t)(kk * 4 + q) * 64 + arow) * 8;
                ulonglong2 u = __builtin_bit_cast(ulonglong2, ah1[kk]);
                while ((u.x == CAN64) | (u.y == CAN64)) {
                    __builtin_amdgcn_s_sleep(1);
                    u.x = ld8(p); u.y = ld8(p + 4);
                }
                s16x8 hf = __builtin_bit_cast(s16x8, u);
                s16x8 w00 = *(const s16x8*)(&Wl[cc][(16 + kk) * 32 + q * 8]);
                s16x8 w10 = *(const s16x8*)(&Wl[16 + cc][(16 + kk) * 32 + q * 8]);
                if (kk & 1) {
                    a0b = __builtin_amdgcn_mfma_f32_16x16x32_bf16(hf, w00, a0b, 0, 0, 0);
                    a1b = __builtin_amdgcn_mfma_f32_16x16x32_bf16(hf, w10, a1b, 0, 0, 0);
                } else {
                    a0  = __builtin_amdgcn_mfma_f32_16x16x32_bf16(hf, w00, a0, 0, 0, 0);
                    a1  = __builtin_amdgcn_mfma_f32_16x16x32_bf16(hf, w10, a1, 0, 0, 0);
                }
            }

            // 4. per-chunk h0(t): K 0..511
            #pragma unroll
            for (int kk = 0; kk < 16; kk++) {
                const unsigned short* p = hb0 + ((size_t)(kk * 4 + q) * 64 + arow) * 8;
                ulonglong2 u = __builtin_bit_cast(ulonglong2, ah0[kk]);
                while ((u.x == CAN64) | (u.y == CAN64)) {
                    __builtin_amdgcn_s_sleep(1);
                    u.x = ld8(p); u.y = ld8(p + 4);
                }
                s16x8 hf = __builtin_bit_cast(s16x8, u);
                s16x8 w00 = *(const s16x8*)(&Wl[cc][kk * 32 + q * 8]);
                s16x8 w10 = *(const s16x8*)(&Wl[16 + cc][kk * 32 + q * 8]);
                if (kk & 1) {
                    a0b = __builtin_amdgcn_mfma_f32_16x16x32_bf16(hf, w00, a0b, 0, 0, 0);
                    a1b = __builtin_amdgcn_mfma_f32_16x16x32_bf16(hf, w10, a1b, 0, 0, 0);
                } else {
                    a0  = __builtin_amdgcn_mfma_f32_16x16x32_bf16(hf, w00, a0, 0, 0, 0);
                    a1  = __builtin_amdgcn_mfma_f32_16x16x32_bf16(hf, w10, a1, 0, 0, 0);
                }
            }
            a0 = a0 + a0b;
            a1 = a1 + a1b;

            float ov[4];
            #pragma unroll
            for (int r = 0; r < 4; r++) {
                float z0 = a0[r], z1 = a1[r];
                float p0 = __shfl_xor(z0, 8, 64);
                float p1 = __shfl_xor(z1, 8, 64);
                float zf = (cc < 8) ? z0 : p0;
                float zi = (cc < 8) ? p0 : z0;
                float zo = (cc < 8) ? z1 : p1;
                float zg = (cc < 8) ? p1 : z1;
                float fg = sig_(zf + 1.0f);            // FORGET_BIAS
                float ig = sig_(zi);
                float og = sig_(zo);
                float gg = tanh_(zg);
                float cn = cst[r] * fg + gg * ig;
                cst[r] = cn;
                float hv = og * tanh_(cn);
                ov[r] = hv;
                int b = bb + r;
                if (cc < 8) hst[b][cc] = f2bf(hv);
                if (t == T_STEPS - 1) {
                    if (cc < 8) hs[(size_t)(64 + b) * 512 + jj] = hv;
                    else        cs[(size_t)(64 + b) * 512 + jj] = cn;
                }
            }

            if (lane < 16) {
                int row = wv * 16 + lane;
                stc(h1s + (size_t)t * 32768 + (size_t)wg * 512 + (size_t)row * 8,
                    *(const s16x8*)(&hst[row][0]));
            }

            // out f32 stores: cached path, off the critical chain
            if (cc >= 8) {
                #pragma unroll
                for (int r = 0; r < 4; r++)
                    out[((size_t)(t * 64 + bb + r)) * 512 + jj] = ov[r];
            }
        }
    }
}

// ---- launch -------------------------------------------------------------

extern "C" void kernel_launch(void* const* d_in, const int* in_sizes, int n_in,
                              void* d_out, int out_size, void* d_ws, size_t ws_size,
                              hipStream_t stream) {
    const float* x  = (const float*)d_in[0];
    const float* W0 = (const float*)d_in[1];
    const float* b0 = (const float*)d_in[2];
    const float* W1 = (const float*)d_in[3];
    const float* b1 = (const float*)d_in[4];
    const float* h0 = (const float*)d_in[5];
    const float* c0 = (const float*)d_in[6];
    float* out = (float*)d_out;

    char* ws = (char*)d_ws;
    unsigned short* xb  = (unsigned short*)(ws);                               // 33,554,432 B
    unsigned short* h0s = (unsigned short*)(ws + 33554432);                    // 33,554,432 B
    unsigned short* h1s = (unsigned short*)(ws + 2 * 33554432);                // 33,554,432 B
    unsigned short* WT0 = (unsigned short*)(ws + 3 * 33554432);                //  4,194,304 B
    unsigned short* WT1 = (unsigned short*)(ws + 3 * 33554432 + 4194304);      //  4,194,304 B
    unsigned short* hi0 = (unsigned short*)(ws + 3 * 33554432 + 2 * 4194304);            // 65,536 B
    unsigned short* hi1 = (unsigned short*)(ws + 3 * 33554432 + 2 * 4194304 + 65536);    // 65,536 B

    // canary-fill the h exchange ring (h0s + h1s are contiguous: 64 MB)
    k_fill_canary<<<16384, 256, 0, stream>>>((unsigned long long*)h0s);
    k_conv_bf16<<<8192, 256, 0, stream>>>(x, xb);
    k_transpose_w<<<dim3(64, 32, 2), dim3(32, 8), 0, stream>>>(W0, W1, WT0, WT1);
    k_hinit<<<256, 256, 0, stream>>>(h0, hi0, hi1);

    float* hs = out + 16777216;            // [2][64][512]
    float* cs = hs + 65536;                // [2][64][512]
    k_lstm_fused8<<<128, 256, 0, stream>>>(xb, hi0, hi1, WT0, WT1, b0, b1, c0,
                                           h0s, h1s, out, hs, cs);
}